// Round 9
// baseline (234.088 us; speedup 1.0000x reference)
//
#include <hip/hip_runtime.h>

typedef unsigned short u16;
typedef unsigned int   u32;

typedef __bf16 bf16x8 __attribute__((ext_vector_type(8)));
typedef float  f32x4  __attribute__((ext_vector_type(4)));

typedef const __attribute__((address_space(1))) void* gas_ptr;
typedef __attribute__((address_space(3))) void* las_ptr;

__device__ __forceinline__ u16 f2bf(float f) {
  u32 u = __builtin_bit_cast(u32, f);
  u += 0x7fffu + ((u >> 16) & 1u);
  return (u16)(u >> 16);
}
__device__ __forceinline__ float bf2f(u16 u) {
  return __builtin_bit_cast(float, ((u32)u) << 16);
}
// packed f32->bf16x2 hardware convert (RTNE), 1 VALU op per pair
__device__ __forceinline__ u32 cvtpk(float a, float b) {
  u32 r;
  asm("v_cvt_pk_bf16_f32 %0, %1, %2" : "=v"(r) : "v"(a), "v"(b));
  return r;
}

// ---------------------------------------------------------------------------
// Kernel 1: BatchNorm over F-channels (stats over B,E) + bf16 cast.
// ---------------------------------------------------------------------------
__global__ __launch_bounds__(256) void bn_norm_kernel(
    const float* __restrict__ x, const float* __restrict__ gamma,
    const float* __restrict__ beta, u16* __restrict__ xn) {
  const int F = 1024, E = 1024;
  int f = blockIdx.x;
  __shared__ float sh[8192];
  __shared__ float ps[4], pq[4], sc[2];

  const float* xf = x + (size_t)f * E;
  float ls = 0.f, lq = 0.f;
  for (int i = threadIdx.x; i < 8192; i += 256) {
    int b = i >> 10, e = i & 1023;
    float v = xf[(size_t)b * F * E + e];
    sh[i] = v;
    ls += v;
    lq += v * v;
  }
  #pragma unroll
  for (int o = 32; o > 0; o >>= 1) {
    ls += __shfl_down(ls, o, 64);
    lq += __shfl_down(lq, o, 64);
  }
  int w = threadIdx.x >> 6;
  if ((threadIdx.x & 63) == 0) { ps[w] = ls; pq[w] = lq; }
  __syncthreads();
  if (threadIdx.x == 0) {
    float s = ps[0] + ps[1] + ps[2] + ps[3];
    float q = pq[0] + pq[1] + pq[2] + pq[3];
    float mean = s * (1.f / 8192.f);
    float var = q * (1.f / 8192.f) - mean * mean;
    float scale = gamma[f] * rsqrtf(var + 1e-5f);
    sc[0] = scale;
    sc[1] = beta[f] - mean * scale;
  }
  __syncthreads();
  float scale = sc[0], shift = sc[1];
  for (int i = threadIdx.x; i < 8192; i += 256) {
    int b = i >> 10, e = i & 1023;
    xn[((size_t)(b * F + f)) * E + e] = f2bf(sh[i] * scale + shift);
  }
}

// ---------------------------------------------------------------------------
// Kernel 2: W_qkv f32 -> bf16
// ---------------------------------------------------------------------------
__global__ __launch_bounds__(256) void wconv_kernel(
    const float* __restrict__ W, u16* __restrict__ Wb) {
  const int total = 3072 * 1024 / 4;
  for (int i = blockIdx.x * 256 + threadIdx.x; i < total; i += gridDim.x * 256) {
    float4 v = ((const float4*)W)[i];
    ushort4 o;
    o.x = f2bf(v.x); o.y = f2bf(v.y); o.z = f2bf(v.z); o.w = f2bf(v.w);
    ((ushort4*)Wb)[i] = o;
  }
}

// ---------------------------------------------------------------------------
// Kernel 3: GEMM  C[m][n] = sum_k A[m][k]*Bw[n][k] + bias[n]  (m97 structure)
// ---------------------------------------------------------------------------
__global__ __launch_bounds__(256) void gemm_qkv_kernel(
    const u16* __restrict__ A, const u16* __restrict__ Bw,
    const float* __restrict__ bias, u16* __restrict__ C) {
  const int K = 1024, N = 3072;
  __shared__ u16 As[128 * 32];
  __shared__ u16 Bs[128 * 32];

  int m0 = blockIdx.x * 128, n0 = blockIdx.y * 128;
  int t = threadIdx.x, lane = t & 63, w = t >> 6;
  int wr = w >> 1, wc = w & 1;
  int r = lane & 15, g = lane >> 4;

  int srow = t >> 2, scol = (t & 3) * 8;
  const u16* gA  = A  + (size_t)(m0 + srow) * K + scol;
  const u16* gA2 = gA + (size_t)64 * K;
  const u16* gB  = Bw + (size_t)(n0 + srow) * K + scol;
  const u16* gB2 = gB + (size_t)64 * K;
  u16* lA  = As + t * 8;
  u16* lA2 = As + 2048 + t * 8;
  u16* lB  = Bs + t * 8;
  u16* lB2 = Bs + 2048 + t * 8;

  f32x4 acc[4][4] = {};

  const u16* pA = As + (size_t)(wr * 64 + r) * 32 + g * 8;
  const u16* pB = Bs + (size_t)(wc * 64 + r) * 32 + g * 8;

  for (int k0 = 0; k0 < K; k0 += 32) {
    __builtin_amdgcn_global_load_lds((gas_ptr)gA,  (las_ptr)lA,  16, 0, 0);
    __builtin_amdgcn_global_load_lds((gas_ptr)gA2, (las_ptr)lA2, 16, 0, 0);
    __builtin_amdgcn_global_load_lds((gas_ptr)gB,  (las_ptr)lB,  16, 0, 0);
    __builtin_amdgcn_global_load_lds((gas_ptr)gB2, (las_ptr)lB2, 16, 0, 0);
    gA += 32; gA2 += 32; gB += 32; gB2 += 32;
    __syncthreads();

    bf16x8 af[4], bfr[4];
    #pragma unroll
    for (int mi = 0; mi < 4; ++mi)
      af[mi] = __builtin_bit_cast(bf16x8, *(const int4*)(pA + mi * 512));
    #pragma unroll
    for (int ni = 0; ni < 4; ++ni)
      bfr[ni] = __builtin_bit_cast(bf16x8, *(const int4*)(pB + ni * 512));
    #pragma unroll
    for (int mi = 0; mi < 4; ++mi)
      #pragma unroll
      for (int ni = 0; ni < 4; ++ni)
        acc[mi][ni] = __builtin_amdgcn_mfma_f32_16x16x32_bf16(af[mi], bfr[ni], acc[mi][ni], 0, 0, 0);
    __syncthreads();
  }

  #pragma unroll
  for (int ni = 0; ni < 4; ++ni) {
    int col = n0 + wc * 64 + ni * 16 + r;
    float bv = bias[col];
    #pragma unroll
    for (int mi = 0; mi < 4; ++mi) {
      int row = m0 + wr * 64 + mi * 16 + g * 4;
      #pragma unroll
      for (int j = 0; j < 4; ++j)
        C[(size_t)(row + j) * N + col] = f2bf(acc[mi][ni][j] + bv);
    }
  }
}

// ---------------------------------------------------------------------------
// Kernel 3b: V transpose WITH baked key permutation (verified R3).
//   Vt[bh][d][kb+m] = V[kb + a(m)][d],  a(m) = bits (m2 m4 m3 m1 m0)
// so the in-register QK softmax output IS the PV B-fragment.
// ---------------------------------------------------------------------------
__global__ __launch_bounds__(256) void vt_kernel(
    const u16* __restrict__ qkv, u16* __restrict__ Vt) {
  __shared__ u16 T[64][72];
  int bh = blockIdx.y, b = bh >> 4, h = bh & 15;
  int f0 = blockIdx.x * 64;
  int t = threadIdx.x;
  int fl = t >> 2, c16 = (t & 3) * 16;
  const u16* src = qkv + (size_t)(b * 1024 + f0 + fl) * 3072 + h * 192 + 128 + c16;
  *(int4*)&T[fl][c16]     = *(const int4*)src;
  *(int4*)&T[fl][c16 + 8] = *(const int4*)(src + 8);
  __syncthreads();
  int dl = t >> 2, fc = (t & 3) * 16;
  u16 buf[16];
  #pragma unroll
  for (int j = 0; j < 16; ++j) {
    int c = fc + j;
    int m = c & 31;
    int a = ((m & 4) << 2) | ((m & 16) >> 1) | ((m & 8) >> 1) | (m & 3);
    buf[j] = T[(c & 32) | a][dl];
  }
  u16* dst = Vt + (size_t)bh * 65536 + (size_t)dl * 1024 + f0 + fc;
  *(int4*)dst       = *(int4*)&buf[0];
  *(int4*)(dst + 8) = *(int4*)&buf[8];
}

// ---------------------------------------------------------------------------
// Kernel 4: flash attention v8 — K LDS-staged (dbuf), V in REGISTERS.
//  - V's PV A-frag is contiguous 16B in Vt per lane: load directly from
//    global (L2-resident) at tile top, consume after softmax (~400cy cover).
//  - K stays LDS double-buffered (shared by 4 waves), 16KB staging LDS.
//  - V loads issued BEFORE the K-stage so the compiler's auto-waitcnt at PV
//    is vmcnt(4) (K prefetch stays in flight).
//  - seeded-C softmax, cvt_pk packing, defer-max, setprio (as R5).
// ---------------------------------------------------------------------------
__global__ __launch_bounds__(256) void attn_kernel(
    const u16* __restrict__ qkv, const u16* __restrict__ Vt,
    float* __restrict__ out) {
  const int F = 1024, NQ = 3072;
  int bid = blockIdx.x;           // 2048 blocks
  int xcd = bid & 7;
  int li  = bid >> 3;             // 0..255
  int bh  = ((li >> 4) << 3) | xcd;
  int ql  = li & 15;
  int w   = threadIdx.x >> 6;
  int lane = threadIdx.x & 63;
  int q = lane & 15, g = lane >> 4;
  int qs = q & 7;
  int q0 = ql * 64 + w * 16;
  int b = bh >> 4, h = bh & 15;

  const u16* base = qkv + (size_t)b * F * NQ + h * 192;
  const u16* VtBH = Vt + (size_t)bh * 65536;

  // LDS: 2 K buffers (8192 u16 = 16KB); epilogue aliases as 4x 64x17 f32
  __shared__ u16 S[8704];

  int i8 = lane >> 3;     // staging row within wave's slice
  int ic = lane & 7;      // staging chunk (16B units)

  // Q fragment, pre-scaled by 1/8 * log2(e) -> softmax in exp2 domain
  const float qscale = 0.125f * 1.4426950408889634f;
  bf16x8 Qf0, Qf1;
  {
    const u16* qp = base + (size_t)(q0 + q) * NQ + g * 8;
    union { int4 v; u16 u[8]; } uu0, uu1;
    uu0.v = *(const int4*)(qp);
    uu1.v = *(const int4*)(qp + 32);
    union { u32 w4[4]; bf16x8 v; } p0, p1;
    #pragma unroll
    for (int j = 0; j < 4; ++j) {
      p0.w4[j] = cvtpk(bf2f(uu0.u[2 * j]) * qscale, bf2f(uu0.u[2 * j + 1]) * qscale);
      p1.w4[j] = cvtpk(bf2f(uu1.u[2 * j]) * qscale, bf2f(uu1.u[2 * j + 1]) * qscale);
    }
    Qf0 = p0.v; Qf1 = p1.v;
  }

  // per-lane V row base: row (dt*16+q) of Vt
  const u16* vl = VtBH + (size_t)q * 1024 + g * 8;

  f32x4 acc[4] = {};
  float m = 0.0f, lsum = 0.f;   // m=0 init (C-seeding needs finite m)

  #define STAGE(buf, kt)                                                       \
    do {                                                                       \
      int kb_ = (kt) * 64;                                                     \
      _Pragma("unroll")                                                        \
      for (int rr = 0; rr < 2; ++rr) {                                         \
        int r_ = rr * 32 + w * 8 + i8;                                         \
        int sc_ = (ic ^ (r_ & 7)) * 8;                                         \
        const u16* ks_ = base + (size_t)(kb_ + r_) * NQ + 64 + sc_;            \
        __builtin_amdgcn_global_load_lds((gas_ptr)ks_,                         \
            (las_ptr)&S[(buf) * 4096 + (rr * 32 + w * 8) * 64], 16, 0, 0);     \
      }                                                                        \
    } while (0)

  STAGE(0, 0);
  __syncthreads();

  int cur = 0;
  for (int kt = 0; kt < 16; ++kt) {
    int kb = kt * 64;

    // ---- early V loads into registers (consumed after softmax)
    int4 vr[8];
    #pragma unroll
    for (int dt = 0; dt < 4; ++dt) {
      const u16* vp = vl + (size_t)dt * 16384 + kb;   // (dt*16)*1024
      vr[dt * 2 + 0] = *(const int4*)(vp);
      vr[dt * 2 + 1] = *(const int4*)(vp + 32);
    }
    __builtin_amdgcn_sched_barrier(0);

    // ---- K(t+1) prefetch into the other LDS buffer
    if (kt < 15) STAGE(cur ^ 1, kt + 1);

    const u16* Kb = &S[cur * 4096];

    // ---- QK^T with C seeded by -m (softmax shift folded into MFMA)
    f32x4 s[4];
    f32x4 seed = {-m, -m, -m, -m};
    __builtin_amdgcn_s_setprio(1);
    #pragma unroll
    for (int ks = 0; ks < 4; ++ks) {
      int row = ks * 16 + q;
      int4 k0 = *(const int4*)&Kb[row * 64 + ((g ^ qs) * 8)];
      int4 k1 = *(const int4*)&Kb[row * 64 + (((4 + g) ^ qs) * 8)];
      f32x4 sv = seed;
      sv = __builtin_amdgcn_mfma_f32_16x16x32_bf16(__builtin_bit_cast(bf16x8, k0), Qf0, sv, 0, 0, 0);
      sv = __builtin_amdgcn_mfma_f32_16x16x32_bf16(__builtin_bit_cast(bf16x8, k1), Qf1, sv, 0, 0, 0);
      s[ks] = sv;
    }
    __builtin_amdgcn_s_setprio(0);

    // ---- per-lane max, max3-shaped tree (s' = qk - m already)
    float a0 = fmaxf(fmaxf(s[0][0], s[0][1]), s[0][2]);
    float a1 = fmaxf(fmaxf(s[0][3], s[1][0]), s[1][1]);
    float a2 = fmaxf(fmaxf(s[1][2], s[1][3]), s[2][0]);
    float a3 = fmaxf(fmaxf(s[2][1], s[2][2]), s[2][3]);
    float a4 = fmaxf(fmaxf(s[3][0], s[3][1]), s[3][2]);
    float tmx = fmaxf(fmaxf(fmaxf(a0, a1), a2), fmaxf(fmaxf(a3, a4), s[3][3]));

    float p[16];
    if (__builtin_expect(__any(tmx > 8.0f), 0)) {
      // rare: rescale to new running max
      float tr = fmaxf(tmx, __shfl_xor(tmx, 16, 64));
      tr = fmaxf(tr, __shfl_xor(tr, 32, 64));
      float dm = fmaxf(tr, 0.f);
      float alpha = exp2f(-dm);
      lsum *= alpha;
      acc[0] *= alpha; acc[1] *= alpha; acc[2] *= alpha; acc[3] *= alpha;
      m += dm;
      #pragma unroll
      for (int ks = 0; ks < 4; ++ks) {
        p[ks * 4 + 0] = exp2f(s[ks][0] - dm);
        p[ks * 4 + 1] = exp2f(s[ks][1] - dm);
        p[ks * 4 + 2] = exp2f(s[ks][2] - dm);
        p[ks * 4 + 3] = exp2f(s[ks][3] - dm);
      }
    } else {
      #pragma unroll
      for (int ks = 0; ks < 4; ++ks) {
        p[ks * 4 + 0] = exp2f(s[ks][0]);
        p[ks * 4 + 1] = exp2f(s[ks][1]);
        p[ks * 4 + 2] = exp2f(s[ks][2]);
        p[ks * 4 + 3] = exp2f(s[ks][3]);
      }
    }
    // balanced psum tree
    float q01 = p[0] + p[1],   q23 = p[2] + p[3];
    float q45 = p[4] + p[5],   q67 = p[6] + p[7];
    float q89 = p[8] + p[9],   qab = p[10] + p[11];
    float qcd = p[12] + p[13], qef = p[14] + p[15];
    lsum += ((q01 + q23) + (q45 + q67)) + ((q89 + qab) + (qcd + qef));

    // ---- pack P via hw cvt_pk (keys pre-permuted in Vt)
    union { u32 w4[4]; bf16x8 v; } pb0, pb1;
    pb0.w4[0] = cvtpk(p[0], p[1]);   pb0.w4[1] = cvtpk(p[2], p[3]);
    pb0.w4[2] = cvtpk(p[4], p[5]);   pb0.w4[3] = cvtpk(p[6], p[7]);
    pb1.w4[0] = cvtpk(p[8], p[9]);   pb1.w4[1] = cvtpk(p[10], p[11]);
    pb1.w4[2] = cvtpk(p[12], p[13]); pb1.w4[3] = cvtpk(p[14], p[15]);

    // ---- PV from register V (compiler auto-waits vmcnt for vr)
    __builtin_amdgcn_s_setprio(1);
    #pragma unroll
    for (int dt = 0; dt < 4; ++dt) {
      acc[dt] = __builtin_amdgcn_mfma_f32_16x16x32_bf16(
          __builtin_bit_cast(bf16x8, vr[dt * 2 + 0]), pb0.v, acc[dt], 0, 0, 0);
      acc[dt] = __builtin_amdgcn_mfma_f32_16x16x32_bf16(
          __builtin_bit_cast(bf16x8, vr[dt * 2 + 1]), pb1.v, acc[dt], 0, 0, 0);
    }
    __builtin_amdgcn_s_setprio(0);

    __syncthreads();
    cur ^= 1;
  }
  #undef STAGE

  // ---- epilogue: reduce lsum, normalize, transpose via LDS (aliased), store
  lsum += __shfl_xor(lsum, 16, 64);
  lsum += __shfl_xor(lsum, 32, 64);
  float inv = 1.0f / lsum;

  float* oT = (float*)S + (size_t)w * 1088;   // per-wave 64x17 region
  #pragma unroll
  for (int dt = 0; dt < 4; ++dt) {
    oT[(dt * 16 + g * 4 + 0) * 17 + q] = acc[dt][0] * inv;
    oT[(dt * 16 + g * 4 + 1) * 17 + q] = acc[dt][1] * inv;
    oT[(dt * 16 + g * 4 + 2) * 17 + q] = acc[dt][2] * inv;
    oT[(dt * 16 + g * 4 + 3) * 17 + q] = acc[dt][3] * inv;
  }
  asm volatile("s_waitcnt lgkmcnt(0)" ::: "memory");
  int oq = lane >> 2, dc = (lane & 3) * 16;
  float* orow = out + (size_t)(b * F + q0 + oq) * 1024 + h * 64 + dc;
  #pragma unroll
  for (int c4 = 0; c4 < 4; ++c4) {
    float4 v;
    v.x = oT[(dc + c4 * 4 + 0) * 17 + oq];
    v.y = oT[(dc + c4 * 4 + 1) * 17 + oq];
    v.z = oT[(dc + c4 * 4 + 2) * 17 + oq];
    v.w = oT[(dc + c4 * 4 + 3) * 17 + oq];
    *(float4*)(orow + c4 * 4) = v;
  }
}

// ---------------------------------------------------------------------------
extern "C" void kernel_launch(void* const* d_in, const int* in_sizes, int n_in,
                              void* d_out, int out_size, void* d_ws, size_t ws_size,
                              hipStream_t stream) {
  const float* x     = (const float*)d_in[0];
  const float* gamma = (const float*)d_in[1];
  const float* beta  = (const float*)d_in[2];
  const float* W     = (const float*)d_in[3];
  const float* bias  = (const float*)d_in[4];
  float* out = (float*)d_out;

  char* ws = (char*)d_ws;
  u16* xn  = (u16*)ws;                                   // 16 MB
  u16* Wb  = (u16*)(ws + (size_t)16 * 1024 * 1024);      //  6 MB
  u16* qkv = (u16*)(ws + (size_t)22 * 1024 * 1024);      // 48 MB
  u16* Vt  = (u16*)(ws + (size_t)70 * 1024 * 1024);      // 16 MB

  bn_norm_kernel<<<1024, 256, 0, stream>>>(x, gamma, beta, xn);
  wconv_kernel<<<768, 256, 0, stream>>>(W, Wb);
  gemm_qkv_kernel<<<dim3(64, 24), 256, 0, stream>>>(xn, Wb, bias, qkv);
  vt_kernel<<<dim3(16, 128), 256, 0, stream>>>(qkv, Vt);
  attn_kernel<<<2048, 256, 0, stream>>>(qkv, Vt, out);
}

// Round 10
// 175.954 us; speedup vs baseline: 1.3304x; 1.3304x over previous
//
#include <hip/hip_runtime.h>

typedef unsigned short u16;
typedef unsigned int   u32;

typedef __bf16 bf16x8 __attribute__((ext_vector_type(8)));
typedef float  f32x4  __attribute__((ext_vector_type(4)));

typedef const __attribute__((address_space(1))) void* gas_ptr;
typedef __attribute__((address_space(3))) void* las_ptr;

__device__ __forceinline__ u16 f2bf(float f) {
  u32 u = __builtin_bit_cast(u32, f);
  u += 0x7fffu + ((u >> 16) & 1u);
  return (u16)(u >> 16);
}
__device__ __forceinline__ float bf2f(u16 u) {
  return __builtin_bit_cast(float, ((u32)u) << 16);
}
// packed f32->bf16x2 hardware convert (RTNE), 1 VALU op per pair
__device__ __forceinline__ u32 cvtpk(float a, float b) {
  u32 r;
  asm("v_cvt_pk_bf16_f32 %0, %1, %2" : "=v"(r) : "v"(a), "v"(b));
  return r;
}

// ---------------------------------------------------------------------------
// Kernel 1: BatchNorm over F-channels (stats over B,E) + bf16 cast.
// ---------------------------------------------------------------------------
__global__ __launch_bounds__(256) void bn_norm_kernel(
    const float* __restrict__ x, const float* __restrict__ gamma,
    const float* __restrict__ beta, u16* __restrict__ xn) {
  const int F = 1024, E = 1024;
  int f = blockIdx.x;
  __shared__ float sh[8192];
  __shared__ float ps[4], pq[4], sc[2];

  const float* xf = x + (size_t)f * E;
  float ls = 0.f, lq = 0.f;
  for (int i = threadIdx.x; i < 8192; i += 256) {
    int b = i >> 10, e = i & 1023;
    float v = xf[(size_t)b * F * E + e];
    sh[i] = v;
    ls += v;
    lq += v * v;
  }
  #pragma unroll
  for (int o = 32; o > 0; o >>= 1) {
    ls += __shfl_down(ls, o, 64);
    lq += __shfl_down(lq, o, 64);
  }
  int w = threadIdx.x >> 6;
  if ((threadIdx.x & 63) == 0) { ps[w] = ls; pq[w] = lq; }
  __syncthreads();
  if (threadIdx.x == 0) {
    float s = ps[0] + ps[1] + ps[2] + ps[3];
    float q = pq[0] + pq[1] + pq[2] + pq[3];
    float mean = s * (1.f / 8192.f);
    float var = q * (1.f / 8192.f) - mean * mean;
    float scale = gamma[f] * rsqrtf(var + 1e-5f);
    sc[0] = scale;
    sc[1] = beta[f] - mean * scale;
  }
  __syncthreads();
  float scale = sc[0], shift = sc[1];
  for (int i = threadIdx.x; i < 8192; i += 256) {
    int b = i >> 10, e = i & 1023;
    xn[((size_t)(b * F + f)) * E + e] = f2bf(sh[i] * scale + shift);
  }
}

// ---------------------------------------------------------------------------
// Kernel 2: W_qkv f32 -> bf16
// ---------------------------------------------------------------------------
__global__ __launch_bounds__(256) void wconv_kernel(
    const float* __restrict__ W, u16* __restrict__ Wb) {
  const int total = 3072 * 1024 / 4;
  for (int i = blockIdx.x * 256 + threadIdx.x; i < total; i += gridDim.x * 256) {
    float4 v = ((const float4*)W)[i];
    ushort4 o;
    o.x = f2bf(v.x); o.y = f2bf(v.y); o.z = f2bf(v.z); o.w = f2bf(v.w);
    ((ushort4*)Wb)[i] = o;
  }
}

// ---------------------------------------------------------------------------
// Kernel 3: GEMM v2 — 256x192 tile, BK=64, 8 waves (2Mx4N), 4 phases/K-tile.
//  C[m][n] = sum_k A[m][k]*Bw[n][k] + bias[n]
//  - source-side swizzle (chunk ^= row&7), linear LDS dest, XOR on ds_read.
//  - per phase: {ds_read frags; stage part of next tile; s_barrier;
//    lgkmcnt(0); setprio(1); 12 MFMA; setprio(0); s_barrier}.
//  - staging issued phases 0-1; boundary vmcnt(0) lands ~3 phases later (free).
//  - grid 512 = 2 even rounds on 256 CUs; XCD-chunked (m,n) mapping.
// ---------------------------------------------------------------------------
__global__ __launch_bounds__(512) void gemm_qkv_kernel(
    const u16* __restrict__ A, const u16* __restrict__ Bw,
    const float* __restrict__ bias, u16* __restrict__ C) {
  const int K = 1024, N = 3072;
  __shared__ u16 GS[57344];   // As: 2x16384 @0 ; Bs: 2x12288 @32768

  int bid = blockIdx.x;
  int xcd = bid & 7, idx = bid >> 3;
  int mt = idx & 31;
  int nt = xcd * 2 + (idx >> 5);
  int m0 = mt * 256, n0 = nt * 192;

  int tid = threadIdx.x;
  int lane = tid & 63, w = tid >> 6;
  int wm = w >> 2, wn = w & 3;        // 2 x 4 waves
  int q = lane & 15, g = lane >> 4;

  int c0 = (g ^ (q & 7)) * 8;         // ks=0 chunk offset (elements)
  int c1 = ((4 + g) ^ (q & 7)) * 8;   // ks=1
  int arow = (wm * 128 + q) * 64;
  int brow = (wn * 48 + q) * 64;

  f32x4 acc[8][3] = {};
  bf16x8 Breg[3][2];

  #define GSTAGE_A(buf, t)                                                     \
    do {                                                                       \
      int k0_ = (t) * 64;                                                      \
      _Pragma("unroll")                                                        \
      for (int j = 0; j < 4; ++j) {                                            \
        int cidx = j * 512 + tid;                                              \
        int row = cidx >> 3, c = cidx & 7;                                     \
        const u16* src = A + (size_t)(m0 + row) * K + k0_ + ((c ^ (row & 7)) * 8); \
        __builtin_amdgcn_global_load_lds((gas_ptr)src,                         \
            (las_ptr)&GS[(buf) * 16384 + cidx * 8], 16, 0, 0);                 \
      }                                                                        \
    } while (0)

  #define GSTAGE_B(buf, t)                                                     \
    do {                                                                       \
      int k0_ = (t) * 64;                                                      \
      _Pragma("unroll")                                                        \
      for (int j = 0; j < 3; ++j) {                                            \
        int cidx = j * 512 + tid;                                              \
        int row = cidx >> 3, c = cidx & 7;                                     \
        const u16* src = Bw + (size_t)(n0 + row) * K + k0_ + ((c ^ (row & 7)) * 8); \
        __builtin_amdgcn_global_load_lds((gas_ptr)src,                         \
            (las_ptr)&GS[32768 + (buf) * 12288 + cidx * 8], 16, 0, 0);         \
      }                                                                        \
    } while (0)

  GSTAGE_A(0, 0);
  GSTAGE_B(0, 0);
  asm volatile("s_waitcnt vmcnt(0)" ::: "memory");
  __builtin_amdgcn_s_barrier();

  for (int t = 0; t < 16; ++t) {
    int cur = t & 1;
    const u16* Ab = &GS[cur * 16384];
    const u16* Bb = &GS[32768 + cur * 12288];
    bool pf = (t + 1) < 16;

    // ================= phase 0: B-frags + A mi 0,1 ; stage A(t+1) ==========
    #pragma unroll
    for (int ni = 0; ni < 3; ++ni) {
      Breg[ni][0] = __builtin_bit_cast(bf16x8, *(const int4*)&Bb[brow + ni * 1024 + c0]);
      Breg[ni][1] = __builtin_bit_cast(bf16x8, *(const int4*)&Bb[brow + ni * 1024 + c1]);
    }
    {
      bf16x8 Ar[2][2];
      #pragma unroll
      for (int mi = 0; mi < 2; ++mi) {
        Ar[mi][0] = __builtin_bit_cast(bf16x8, *(const int4*)&Ab[arow + mi * 1024 + c0]);
        Ar[mi][1] = __builtin_bit_cast(bf16x8, *(const int4*)&Ab[arow + mi * 1024 + c1]);
      }
      if (pf) GSTAGE_A(cur ^ 1, t + 1);
      __builtin_amdgcn_s_barrier();
      asm volatile("s_waitcnt lgkmcnt(0)" ::: "memory");
      __builtin_amdgcn_sched_barrier(0);
      __builtin_amdgcn_s_setprio(1);
      #pragma unroll
      for (int mi = 0; mi < 2; ++mi)
        #pragma unroll
        for (int ni = 0; ni < 3; ++ni) {
          acc[mi][ni] = __builtin_amdgcn_mfma_f32_16x16x32_bf16(Ar[mi][0], Breg[ni][0], acc[mi][ni], 0, 0, 0);
          acc[mi][ni] = __builtin_amdgcn_mfma_f32_16x16x32_bf16(Ar[mi][1], Breg[ni][1], acc[mi][ni], 0, 0, 0);
        }
      __builtin_amdgcn_s_setprio(0);
      __builtin_amdgcn_s_barrier();
    }

    // ================= phases 1..3: A mi 2p,2p+1 ; stage B(t+1) at p=1 =====
    #define GPHASE(p, STG)                                                     \
    {                                                                          \
      bf16x8 Ar[2][2];                                                         \
      _Pragma("unroll")                                                        \
      for (int mi = 0; mi < 2; ++mi) {                                         \
        int mr = ((p) * 2 + mi) * 1024;                                        \
        Ar[mi][0] = __builtin_bit_cast(bf16x8, *(const int4*)&Ab[arow + mr + c0]); \
        Ar[mi][1] = __builtin_bit_cast(bf16x8, *(const int4*)&Ab[arow + mr + c1]); \
      }                                                                        \
      STG;                                                                     \
      __builtin_amdgcn_s_barrier();                                            \
      asm volatile("s_waitcnt lgkmcnt(0)" ::: "memory");                       \
      __builtin_amdgcn_sched_barrier(0);                                       \
      __builtin_amdgcn_s_setprio(1);                                           \
      _Pragma("unroll")                                                        \
      for (int mi = 0; mi < 2; ++mi)                                           \
        _Pragma("unroll")                                                      \
        for (int ni = 0; ni < 3; ++ni) {                                       \
          acc[(p) * 2 + mi][ni] = __builtin_amdgcn_mfma_f32_16x16x32_bf16(     \
              Ar[mi][0], Breg[ni][0], acc[(p) * 2 + mi][ni], 0, 0, 0);         \
          acc[(p) * 2 + mi][ni] = __builtin_amdgcn_mfma_f32_16x16x32_bf16(     \
              Ar[mi][1], Breg[ni][1], acc[(p) * 2 + mi][ni], 0, 0, 0);         \
        }                                                                      \
      __builtin_amdgcn_s_setprio(0);                                           \
    }

    GPHASE(1, if (pf) GSTAGE_B(cur ^ 1, t + 1));
    __builtin_amdgcn_s_barrier();
    GPHASE(2, );
    __builtin_amdgcn_s_barrier();
    GPHASE(3, );
    // boundary: staged loads (issued phases 0-1, ~900cy ago) must be in LDS
    asm volatile("s_waitcnt vmcnt(0)" ::: "memory");
    __builtin_amdgcn_s_barrier();
    #undef GPHASE
  }
  #undef GSTAGE_A
  #undef GSTAGE_B

  // ---- epilogue: bias + bf16 store (m97-verified C/D mapping)
  #pragma unroll
  for (int ni = 0; ni < 3; ++ni) {
    int col = n0 + wn * 48 + ni * 16 + q;
    float bv = bias[col];
    #pragma unroll
    for (int mi = 0; mi < 8; ++mi) {
      int row = m0 + wm * 128 + mi * 16 + g * 4;
      #pragma unroll
      for (int j = 0; j < 4; ++j)
        C[(size_t)(row + j) * N + col] = f2bf(acc[mi][ni][j] + bv);
    }
  }
}

// ---------------------------------------------------------------------------
// Kernel 3b: V transpose WITH baked key permutation (verified R3).
//   Vt[bh][d][kb+m] = V[kb + a(m)][d],  a(m) = bits (m2 m4 m3 m1 m0)
// so the in-register QK softmax output IS the PV B-fragment.
// ---------------------------------------------------------------------------
__global__ __launch_bounds__(256) void vt_kernel(
    const u16* __restrict__ qkv, u16* __restrict__ Vt) {
  __shared__ u16 T[64][72];
  int bh = blockIdx.y, b = bh >> 4, h = bh & 15;
  int f0 = blockIdx.x * 64;
  int t = threadIdx.x;
  int fl = t >> 2, c16 = (t & 3) * 16;
  const u16* src = qkv + (size_t)(b * 1024 + f0 + fl) * 3072 + h * 192 + 128 + c16;
  *(int4*)&T[fl][c16]     = *(const int4*)src;
  *(int4*)&T[fl][c16 + 8] = *(const int4*)(src + 8);
  __syncthreads();
  int dl = t >> 2, fc = (t & 3) * 16;
  u16 buf[16];
  #pragma unroll
  for (int j = 0; j < 16; ++j) {
    int c = fc + j;
    int m = c & 31;
    int a = ((m & 4) << 2) | ((m & 16) >> 1) | ((m & 8) >> 1) | (m & 3);
    buf[j] = T[(c & 32) | a][dl];
  }
  u16* dst = Vt + (size_t)bh * 65536 + (size_t)dl * 1024 + f0 + fc;
  *(int4*)dst       = *(int4*)&buf[0];
  *(int4*)(dst + 8) = *(int4*)&buf[8];
}

// ---------------------------------------------------------------------------
// Kernel 4: flash attention v7 (R7 verbatim — best measured, 87.5us).
// Triple-buffered K/V, counted-vmcnt pipeline, prefetch depth 2.
// ---------------------------------------------------------------------------
__global__ __launch_bounds__(256) void attn_kernel(
    const u16* __restrict__ qkv, const u16* __restrict__ Vt,
    float* __restrict__ out) {
  const int F = 1024, NQ = 3072;
  int bid = blockIdx.x;           // 2048 blocks
  int xcd = bid & 7;
  int li  = bid >> 3;             // 0..255
  int bh  = ((li >> 4) << 3) | xcd;
  int ql  = li & 15;
  int w   = threadIdx.x >> 6;
  int lane = threadIdx.x & 63;
  int q = lane & 15, g = lane >> 4;
  int qs = q & 7;
  int q0 = ql * 64 + w * 16;
  int b = bh >> 4, h = bh & 15;

  const u16* base = qkv + (size_t)b * F * NQ + h * 192;
  const u16* VtBH = Vt + (size_t)bh * 65536;

  // 3 K bufs @ 0/4096/8192, 3 V bufs @ 12288/16384/20480 (u16 units; 48 KB)
  __shared__ u16 S[24576];

  int i8 = lane >> 3;     // staging row within wave's slice
  int ic = lane & 7;      // staging chunk (16B units)

  const float qscale = 0.125f * 1.4426950408889634f;
  bf16x8 Qf0, Qf1;
  {
    const u16* qp = base + (size_t)(q0 + q) * NQ + g * 8;
    union { int4 v; u16 u[8]; } uu0, uu1;
    uu0.v = *(const int4*)(qp);
    uu1.v = *(const int4*)(qp + 32);
    union { u32 w4[4]; bf16x8 v; } p0, p1;
    #pragma unroll
    for (int j = 0; j < 4; ++j) {
      p0.w4[j] = cvtpk(bf2f(uu0.u[2 * j]) * qscale, bf2f(uu0.u[2 * j + 1]) * qscale);
      p1.w4[j] = cvtpk(bf2f(uu1.u[2 * j]) * qscale, bf2f(uu1.u[2 * j + 1]) * qscale);
    }
    Qf0 = p0.v; Qf1 = p1.v;
  }

  f32x4 acc[4] = {};
  float m = 0.0f, lsum = 0.f;   // m=0 init (C-seeding needs finite m)

  #define STAGE(buf, kt)                                                       \
    do {                                                                       \
      int kb_ = (kt) * 64;                                                     \
      _Pragma("unroll")                                                        \
      for (int rr = 0; rr < 2; ++rr) {                                         \
        int r_ = rr * 32 + w * 8 + i8;                                         \
        int sc_ = (ic ^ (r_ & 7)) * 8;                                         \
        const u16* ks_ = base + (size_t)(kb_ + r_) * NQ + 64 + sc_;            \
        const u16* vs_ = VtBH + (size_t)r_ * 1024 + kb_ + sc_;                 \
        __builtin_amdgcn_global_load_lds((gas_ptr)ks_,                         \
            (las_ptr)&S[(buf) * 4096 + (rr * 32 + w * 8) * 64], 16, 0, 0);     \
        __builtin_amdgcn_global_load_lds((gas_ptr)vs_,                         \
            (las_ptr)&S[12288 + (buf) * 4096 + (rr * 32 + w * 8) * 64], 16, 0, 0);\
      }                                                                        \
    } while (0)

  __builtin_amdgcn_sched_barrier(0);
  STAGE(0, 0);
  STAGE(1, 1);
  asm volatile("s_waitcnt vmcnt(4)" ::: "memory");
  __builtin_amdgcn_s_barrier();
  __builtin_amdgcn_sched_barrier(0);

  int cur = 0, stg = 2;
  for (int kt = 0; kt < 16; ++kt) {
    if (kt < 14) STAGE(stg, kt + 2);

    const u16* Kb = &S[cur * 4096];
    const u16* Vb = &S[12288 + cur * 4096];

    f32x4 s[4];
    f32x4 seed = {-m, -m, -m, -m};
    __builtin_amdgcn_s_setprio(1);
    #pragma unroll
    for (int ks = 0; ks < 4; ++ks) {
      int row = ks * 16 + q;
      int4 k0 = *(const int4*)&Kb[row * 64 + ((g ^ qs) * 8)];
      int4 k1 = *(const int4*)&Kb[row * 64 + (((4 + g) ^ qs) * 8)];
      f32x4 sv = seed;
      sv = __builtin_amdgcn_mfma_f32_16x16x32_bf16(__builtin_bit_cast(bf16x8, k0), Qf0, sv, 0, 0, 0);
      sv = __builtin_amdgcn_mfma_f32_16x16x32_bf16(__builtin_bit_cast(bf16x8, k1), Qf1, sv, 0, 0, 0);
      s[ks] = sv;
    }
    __builtin_amdgcn_s_setprio(0);

    float a0 = fmaxf(fmaxf(s[0][0], s[0][1]), s[0][2]);
    float a1 = fmaxf(fmaxf(s[0][3], s[1][0]), s[1][1]);
    float a2 = fmaxf(fmaxf(s[1][2], s[1][3]), s[2][0]);
    float a3 = fmaxf(fmaxf(s[2][1], s[2][2]), s[2][3]);
    float a4 = fmaxf(fmaxf(s[3][0], s[3][1]), s[3][2]);
    float tmx = fmaxf(fmaxf(fmaxf(a0, a1), a2), fmaxf(fmaxf(a3, a4), s[3][3]));

    float p[16];
    if (__builtin_expect(__any(tmx > 8.0f), 0)) {
      float tr = fmaxf(tmx, __shfl_xor(tmx, 16, 64));
      tr = fmaxf(tr, __shfl_xor(tr, 32, 64));
      float dm = fmaxf(tr, 0.f);
      float alpha = exp2f(-dm);
      lsum *= alpha;
      acc[0] *= alpha; acc[1] *= alpha; acc[2] *= alpha; acc[3] *= alpha;
      m += dm;
      #pragma unroll
      for (int ks = 0; ks < 4; ++ks) {
        p[ks * 4 + 0] = exp2f(s[ks][0] - dm);
        p[ks * 4 + 1] = exp2f(s[ks][1] - dm);
        p[ks * 4 + 2] = exp2f(s[ks][2] - dm);
        p[ks * 4 + 3] = exp2f(s[ks][3] - dm);
      }
    } else {
      #pragma unroll
      for (int ks = 0; ks < 4; ++ks) {
        p[ks * 4 + 0] = exp2f(s[ks][0]);
        p[ks * 4 + 1] = exp2f(s[ks][1]);
        p[ks * 4 + 2] = exp2f(s[ks][2]);
        p[ks * 4 + 3] = exp2f(s[ks][3]);
      }
    }
    float q01 = p[0] + p[1],   q23 = p[2] + p[3];
    float q45 = p[4] + p[5],   q67 = p[6] + p[7];
    float q89 = p[8] + p[9],   qab = p[10] + p[11];
    float qcd = p[12] + p[13], qef = p[14] + p[15];
    lsum += ((q01 + q23) + (q45 + q67)) + ((q89 + qab) + (qcd + qef));

    union { u32 w4[4]; bf16x8 v; } pb0, pb1;
    pb0.w4[0] = cvtpk(p[0], p[1]);   pb0.w4[1] = cvtpk(p[2], p[3]);
    pb0.w4[2] = cvtpk(p[4], p[5]);   pb0.w4[3] = cvtpk(p[6], p[7]);
    pb1.w4[0] = cvtpk(p[8], p[9]);   pb1.w4[1] = cvtpk(p[10], p[11]);
    pb1.w4[2] = cvtpk(p[12], p[13]); pb1.w4[3] = cvtpk(p[14], p[15]);

    __builtin_amdgcn_s_setprio(1);
    #pragma unroll
    for (int dt = 0; dt < 4; ++dt) {
      int row = dt * 16 + q;
      int4 v0 = *(const int4*)&Vb[row * 64 + ((g ^ qs) * 8)];
      int4 v1 = *(const int4*)&Vb[row * 64 + (((4 + g) ^ qs) * 8)];
      acc[dt] = __builtin_amdgcn_mfma_f32_16x16x32_bf16(__builtin_bit_cast(bf16x8, v0), pb0.v, acc[dt], 0, 0, 0);
      acc[dt] = __builtin_amdgcn_mfma_f32_16x16x32_bf16(__builtin_bit_cast(bf16x8, v1), pb1.v, acc[dt], 0, 0, 0);
    }
    __builtin_amdgcn_s_setprio(0);

    if (kt < 14) {
      asm volatile("s_waitcnt vmcnt(4)" ::: "memory");
    } else {
      asm volatile("s_waitcnt vmcnt(0)" ::: "memory");
    }
    __builtin_amdgcn_s_barrier();
    __builtin_amdgcn_sched_barrier(0);

    cur = (cur == 2) ? 0 : cur + 1;
    stg = (stg == 2) ? 0 : stg + 1;
  }
  #undef STAGE

  lsum += __shfl_xor(lsum, 16, 64);
  lsum += __shfl_xor(lsum, 32, 64);
  float inv = 1.0f / lsum;

  float* oT = (float*)S + (size_t)w * 1088;   // per-wave 64x17 region
  #pragma unroll
  for (int dt = 0; dt < 4; ++dt) {
    oT[(dt * 16 + g * 4 + 0) * 17 + q] = acc[dt][0] * inv;
    oT[(dt * 16 + g * 4 + 1) * 17 + q] = acc[dt][1] * inv;
    oT[(dt * 16 + g * 4 + 2) * 17 + q] = acc[dt][2] * inv;
    oT[(dt * 16 + g * 4 + 3) * 17 + q] = acc[dt][3] * inv;
  }
  asm volatile("s_waitcnt lgkmcnt(0)" ::: "memory");
  int oq = lane >> 2, dc = (lane & 3) * 16;
  float* orow = out + (size_t)(b * F + q0 + oq) * 1024 + h * 64 + dc;
  #pragma unroll
  for (int c4 = 0; c4 < 4; ++c4) {
    float4 v;
    v.x = oT[(dc + c4 * 4 + 0) * 17 + oq];
    v.y = oT[(dc + c4 * 4 + 1) * 17 + oq];
    v.z = oT[(dc + c4 * 4 + 2) * 17 + oq];
    v.w = oT[(dc + c4 * 4 + 3) * 17 + oq];
    *(float4*)(orow + c4 * 4) = v;
  }
}

// ---------------------------------------------------------------------------
extern "C" void kernel_launch(void* const* d_in, const int* in_sizes, int n_in,
                              void* d_out, int out_size, void* d_ws, size_t ws_size,
                              hipStream_t stream) {
  const float* x     = (const float*)d_in[0];
  const float* gamma = (const float*)d_in[1];
  const float* beta  = (const float*)d_in[2];
  const float* W     = (const float*)d_in[3];
  const float* bias  = (const float*)d_in[4];
  float* out = (float*)d_out;

  char* ws = (char*)d_ws;
  u16* xn  = (u16*)ws;                                   // 16 MB
  u16* Wb  = (u16*)(ws + (size_t)16 * 1024 * 1024);      //  6 MB
  u16* qkv = (u16*)(ws + (size_t)22 * 1024 * 1024);      // 48 MB
  u16* Vt  = (u16*)(ws + (size_t)70 * 1024 * 1024);      // 16 MB

  bn_norm_kernel<<<1024, 256, 0, stream>>>(x, gamma, beta, xn);
  wconv_kernel<<<768, 256, 0, stream>>>(W, Wb);
  gemm_qkv_kernel<<<512, 512, 0, stream>>>(xn, Wb, bias, qkv);
  vt_kernel<<<dim3(16, 128), 256, 0, stream>>>(qkv, Vt);
  attn_kernel<<<2048, 256, 0, stream>>>(qkv, Vt, out);
}

// Round 11
// 172.673 us; speedup vs baseline: 1.3557x; 1.0190x over previous
//
#include <hip/hip_runtime.h>

typedef unsigned short u16;
typedef unsigned int   u32;

typedef __bf16 bf16x8 __attribute__((ext_vector_type(8)));
typedef float  f32x4  __attribute__((ext_vector_type(4)));

typedef const __attribute__((address_space(1))) void* gas_ptr;
typedef __attribute__((address_space(3))) void* las_ptr;

__device__ __forceinline__ u16 f2bf(float f) {
  u32 u = __builtin_bit_cast(u32, f);
  u += 0x7fffu + ((u >> 16) & 1u);
  return (u16)(u >> 16);
}
__device__ __forceinline__ float bf2f(u16 u) {
  return __builtin_bit_cast(float, ((u32)u) << 16);
}
// packed f32->bf16x2 hardware convert (RTNE), 1 VALU op per pair
__device__ __forceinline__ u32 cvtpk(float a, float b) {
  u32 r;
  asm("v_cvt_pk_bf16_f32 %0, %1, %2" : "=v"(r) : "v"(a), "v"(b));
  return r;
}

// ---------------------------------------------------------------------------
// Kernel 1: BatchNorm over F-channels (stats over B,E) + bf16 cast.
// ---------------------------------------------------------------------------
__global__ __launch_bounds__(256) void bn_norm_kernel(
    const float* __restrict__ x, const float* __restrict__ gamma,
    const float* __restrict__ beta, u16* __restrict__ xn) {
  const int F = 1024, E = 1024;
  int f = blockIdx.x;
  __shared__ float sh[8192];
  __shared__ float ps[4], pq[4], sc[2];

  const float* xf = x + (size_t)f * E;
  float ls = 0.f, lq = 0.f;
  for (int i = threadIdx.x; i < 8192; i += 256) {
    int b = i >> 10, e = i & 1023;
    float v = xf[(size_t)b * F * E + e];
    sh[i] = v;
    ls += v;
    lq += v * v;
  }
  #pragma unroll
  for (int o = 32; o > 0; o >>= 1) {
    ls += __shfl_down(ls, o, 64);
    lq += __shfl_down(lq, o, 64);
  }
  int w = threadIdx.x >> 6;
  if ((threadIdx.x & 63) == 0) { ps[w] = ls; pq[w] = lq; }
  __syncthreads();
  if (threadIdx.x == 0) {
    float s = ps[0] + ps[1] + ps[2] + ps[3];
    float q = pq[0] + pq[1] + pq[2] + pq[3];
    float mean = s * (1.f / 8192.f);
    float var = q * (1.f / 8192.f) - mean * mean;
    float scale = gamma[f] * rsqrtf(var + 1e-5f);
    sc[0] = scale;
    sc[1] = beta[f] - mean * scale;
  }
  __syncthreads();
  float scale = sc[0], shift = sc[1];
  for (int i = threadIdx.x; i < 8192; i += 256) {
    int b = i >> 10, e = i & 1023;
    xn[((size_t)(b * F + f)) * E + e] = f2bf(sh[i] * scale + shift);
  }
}

// ---------------------------------------------------------------------------
// Kernel 2: W_qkv f32 -> bf16, reordered into Wqk[2048][1024] and Wv[1024][1024].
//  Wqk row r' : h = r'>>7, s = r'&127  <- W row h*192 + s   (Q:0-63, K:64-127)
//  Wv  row r'': h = r''>>6, d = r''&63 <- W row h*192 + 128 + d
// ---------------------------------------------------------------------------
__global__ __launch_bounds__(256) void wconv_kernel(
    const float* __restrict__ W, u16* __restrict__ Wqk, u16* __restrict__ Wv) {
  const int total = 3072 * 256;   // float4 groups
  for (int i = blockIdx.x * 256 + threadIdx.x; i < total; i += gridDim.x * 256) {
    int row = i >> 8, c4 = (i & 255) * 4;
    int srow;
    u16* dst;
    if (row < 2048) {
      srow = (row >> 7) * 192 + (row & 127);
      dst = Wqk + (size_t)row * 1024 + c4;
    } else {
      int rv = row - 2048;
      srow = (rv >> 6) * 192 + 128 + (rv & 63);
      dst = Wv + (size_t)rv * 1024 + c4;
    }
    float4 v = *(const float4*)(W + (size_t)srow * 1024 + c4);
    ushort4 o;
    o.x = f2bf(v.x); o.y = f2bf(v.y); o.z = f2bf(v.z); o.w = f2bf(v.w);
    *(ushort4*)dst = o;
  }
}

// ---------------------------------------------------------------------------
// Kernel 3: GEMM#1 (m97): qk[m][col] = xn[m]·Wqk[col] + bias  (N=2048)
// bias remap: orig = (col>>7)*192 + (col&127)
// ---------------------------------------------------------------------------
__global__ __launch_bounds__(256) void gemm_qk_kernel(
    const u16* __restrict__ A, const u16* __restrict__ Bw,
    const float* __restrict__ bias, u16* __restrict__ C) {
  const int K = 1024, N = 2048;
  __shared__ u16 As[128 * 32];
  __shared__ u16 Bs[128 * 32];

  int m0 = blockIdx.x * 128, n0 = blockIdx.y * 128;
  int t = threadIdx.x, lane = t & 63, w = t >> 6;
  int wr = w >> 1, wc = w & 1;
  int r = lane & 15, g = lane >> 4;

  int srow = t >> 2, scol = (t & 3) * 8;
  const u16* gA  = A  + (size_t)(m0 + srow) * K + scol;
  const u16* gA2 = gA + (size_t)64 * K;
  const u16* gB  = Bw + (size_t)(n0 + srow) * K + scol;
  const u16* gB2 = gB + (size_t)64 * K;
  u16* lA  = As + t * 8;
  u16* lA2 = As + 2048 + t * 8;
  u16* lB  = Bs + t * 8;
  u16* lB2 = Bs + 2048 + t * 8;

  f32x4 acc[4][4] = {};

  const u16* pA = As + (size_t)(wr * 64 + r) * 32 + g * 8;
  const u16* pB = Bs + (size_t)(wc * 64 + r) * 32 + g * 8;

  for (int k0 = 0; k0 < K; k0 += 32) {
    __builtin_amdgcn_global_load_lds((gas_ptr)gA,  (las_ptr)lA,  16, 0, 0);
    __builtin_amdgcn_global_load_lds((gas_ptr)gA2, (las_ptr)lA2, 16, 0, 0);
    __builtin_amdgcn_global_load_lds((gas_ptr)gB,  (las_ptr)lB,  16, 0, 0);
    __builtin_amdgcn_global_load_lds((gas_ptr)gB2, (las_ptr)lB2, 16, 0, 0);
    gA += 32; gA2 += 32; gB += 32; gB2 += 32;
    __syncthreads();

    bf16x8 af[4], bfr[4];
    #pragma unroll
    for (int mi = 0; mi < 4; ++mi)
      af[mi] = __builtin_bit_cast(bf16x8, *(const int4*)(pA + mi * 512));
    #pragma unroll
    for (int ni = 0; ni < 4; ++ni)
      bfr[ni] = __builtin_bit_cast(bf16x8, *(const int4*)(pB + ni * 512));
    #pragma unroll
    for (int mi = 0; mi < 4; ++mi)
      #pragma unroll
      for (int ni = 0; ni < 4; ++ni)
        acc[mi][ni] = __builtin_amdgcn_mfma_f32_16x16x32_bf16(af[mi], bfr[ni], acc[mi][ni], 0, 0, 0);
    __syncthreads();
  }

  #pragma unroll
  for (int ni = 0; ni < 4; ++ni) {
    int col = n0 + wc * 64 + ni * 16 + r;
    float bv = bias[(col >> 7) * 192 + (col & 127)];
    #pragma unroll
    for (int mi = 0; mi < 4; ++mi) {
      int row = m0 + wr * 64 + mi * 16 + g * 4;
      #pragma unroll
      for (int j = 0; j < 4; ++j)
        C[(size_t)(row + j) * N + col] = f2bf(acc[mi][ni][j] + bv);
    }
  }
}

// ---------------------------------------------------------------------------
// Kernel 3b: GEMM#2 (m97 loop): V = xn·Wv + bias, written DIRECTLY to Vt with
// the baked key permutation (vt_kernel eliminated).
//   Forward map (R3-verified): Vt[bh][d][kb+m] = V[kb + a(m)][d],
//     a(m) = ((m&4)<<2)|((m&16)>>1)|((m&8)>>1)|(m&3)
//   Inverse used here: source row f (s=f&31) lands at m = a^-1(s)
//     = ((s&16)>>2)|((s&8)<<1)|((s&4)<<1)|(s&3)
//   For lane (g) / frag (mi): s = (mi&1)*16 + g*4 + j  ->
//     m = (g>>1)*16 + (g&1)*8 + (mi&1)*4 + j   (contiguous in j -> 8B store)
// ---------------------------------------------------------------------------
__global__ __launch_bounds__(256) void gemm_v_kernel(
    const u16* __restrict__ A, const u16* __restrict__ Bw,
    const float* __restrict__ bias, u16* __restrict__ Vt) {
  const int K = 1024;
  __shared__ u16 As[128 * 32];
  __shared__ u16 Bs[128 * 32];

  int m0 = blockIdx.x * 128, n0 = blockIdx.y * 128;
  int t = threadIdx.x, lane = t & 63, w = t >> 6;
  int wr = w >> 1, wc = w & 1;
  int r = lane & 15, g = lane >> 4;

  int srow = t >> 2, scol = (t & 3) * 8;
  const u16* gA  = A  + (size_t)(m0 + srow) * K + scol;
  const u16* gA2 = gA + (size_t)64 * K;
  const u16* gB  = Bw + (size_t)(n0 + srow) * K + scol;
  const u16* gB2 = gB + (size_t)64 * K;
  u16* lA  = As + t * 8;
  u16* lA2 = As + 2048 + t * 8;
  u16* lB  = Bs + t * 8;
  u16* lB2 = Bs + 2048 + t * 8;

  f32x4 acc[4][4] = {};

  const u16* pA = As + (size_t)(wr * 64 + r) * 32 + g * 8;
  const u16* pB = Bs + (size_t)(wc * 64 + r) * 32 + g * 8;

  for (int k0 = 0; k0 < K; k0 += 32) {
    __builtin_amdgcn_global_load_lds((gas_ptr)gA,  (las_ptr)lA,  16, 0, 0);
    __builtin_amdgcn_global_load_lds((gas_ptr)gA2, (las_ptr)lA2, 16, 0, 0);
    __builtin_amdgcn_global_load_lds((gas_ptr)gB,  (las_ptr)lB,  16, 0, 0);
    __builtin_amdgcn_global_load_lds((gas_ptr)gB2, (las_ptr)lB2, 16, 0, 0);
    gA += 32; gA2 += 32; gB += 32; gB2 += 32;
    __syncthreads();

    bf16x8 af[4], bfr[4];
    #pragma unroll
    for (int mi = 0; mi < 4; ++mi)
      af[mi] = __builtin_bit_cast(bf16x8, *(const int4*)(pA + mi * 512));
    #pragma unroll
    for (int ni = 0; ni < 4; ++ni)
      bfr[ni] = __builtin_bit_cast(bf16x8, *(const int4*)(pB + ni * 512));
    #pragma unroll
    for (int mi = 0; mi < 4; ++mi)
      #pragma unroll
      for (int ni = 0; ni < 4; ++ni)
        acc[mi][ni] = __builtin_amdgcn_mfma_f32_16x16x32_bf16(af[mi], bfr[ni], acc[mi][ni], 0, 0, 0);
    __syncthreads();
  }

  // ---- transposed epilogue into Vt (b is block-uniform: 128 | 1024)
  int b_ = m0 >> 10;
  #pragma unroll
  for (int ni = 0; ni < 4; ++ni) {
    int col = n0 + wc * 64 + ni * 16 + r;     // V output dim: h*64 + d
    int h_ = col >> 6, d_ = col & 63;
    float bv = bias[h_ * 192 + 128 + d_];
    u16* vtd = Vt + (size_t)(b_ * 16 + h_) * 65536 + (size_t)d_ * 1024;
    #pragma unroll
    for (int mi = 0; mi < 4; ++mi) {
      int fbase = (m0 & 1023) + wr * 64 + mi * 16 + g * 4;
      int pos = (fbase & ~31) + ((g >> 1) * 16) + ((g & 1) * 8) + ((mi & 1) * 4);
      uint2 st;
      st.x = cvtpk(acc[mi][ni][0] + bv, acc[mi][ni][1] + bv);
      st.y = cvtpk(acc[mi][ni][2] + bv, acc[mi][ni][3] + bv);
      *(uint2*)(vtd + pos) = st;
    }
  }
}

// ---------------------------------------------------------------------------
// Kernel 4: flash attention v7 (best measured, 87.5us) — adapted to the
// qk[8192][2048] layout (head h at col h*128: Q 0-63, K 64-127).
// Triple-buffered K/V, counted-vmcnt pipeline, prefetch depth 2.
// ---------------------------------------------------------------------------
__global__ __launch_bounds__(256) void attn_kernel(
    const u16* __restrict__ qk, const u16* __restrict__ Vt,
    float* __restrict__ out) {
  const int F = 1024, NQ = 2048;
  int bid = blockIdx.x;           // 2048 blocks
  int xcd = bid & 7;
  int li  = bid >> 3;             // 0..255
  int bh  = ((li >> 4) << 3) | xcd;
  int ql  = li & 15;
  int w   = threadIdx.x >> 6;
  int lane = threadIdx.x & 63;
  int q = lane & 15, g = lane >> 4;
  int qs = q & 7;
  int q0 = ql * 64 + w * 16;
  int b = bh >> 4, h = bh & 15;

  const u16* base = qk + (size_t)b * F * NQ + h * 128;
  const u16* VtBH = Vt + (size_t)bh * 65536;

  // 3 K bufs @ 0/4096/8192, 3 V bufs @ 12288/16384/20480 (u16 units; 48 KB)
  __shared__ u16 S[24576];

  int i8 = lane >> 3;     // staging row within wave's slice
  int ic = lane & 7;      // staging chunk (16B units)

  const float qscale = 0.125f * 1.4426950408889634f;
  bf16x8 Qf0, Qf1;
  {
    const u16* qp = base + (size_t)(q0 + q) * NQ + g * 8;
    union { int4 v; u16 u[8]; } uu0, uu1;
    uu0.v = *(const int4*)(qp);
    uu1.v = *(const int4*)(qp + 32);
    union { u32 w4[4]; bf16x8 v; } p0, p1;
    #pragma unroll
    for (int j = 0; j < 4; ++j) {
      p0.w4[j] = cvtpk(bf2f(uu0.u[2 * j]) * qscale, bf2f(uu0.u[2 * j + 1]) * qscale);
      p1.w4[j] = cvtpk(bf2f(uu1.u[2 * j]) * qscale, bf2f(uu1.u[2 * j + 1]) * qscale);
    }
    Qf0 = p0.v; Qf1 = p1.v;
  }

  f32x4 acc[4] = {};
  float m = 0.0f, lsum = 0.f;   // m=0 init (C-seeding needs finite m)

  #define STAGE(buf, kt)                                                       \
    do {                                                                       \
      int kb_ = (kt) * 64;                                                     \
      _Pragma("unroll")                                                        \
      for (int rr = 0; rr < 2; ++rr) {                                         \
        int r_ = rr * 32 + w * 8 + i8;                                         \
        int sc_ = (ic ^ (r_ & 7)) * 8;                                         \
        const u16* ks_ = base + (size_t)(kb_ + r_) * NQ + 64 + sc_;            \
        const u16* vs_ = VtBH + (size_t)r_ * 1024 + kb_ + sc_;                 \
        __builtin_amdgcn_global_load_lds((gas_ptr)ks_,                         \
            (las_ptr)&S[(buf) * 4096 + (rr * 32 + w * 8) * 64], 16, 0, 0);     \
        __builtin_amdgcn_global_load_lds((gas_ptr)vs_,                         \
            (las_ptr)&S[12288 + (buf) * 4096 + (rr * 32 + w * 8) * 64], 16, 0, 0);\
      }                                                                        \
    } while (0)

  __builtin_amdgcn_sched_barrier(0);
  STAGE(0, 0);
  STAGE(1, 1);
  asm volatile("s_waitcnt vmcnt(4)" ::: "memory");
  __builtin_amdgcn_s_barrier();
  __builtin_amdgcn_sched_barrier(0);

  int cur = 0, stg = 2;
  for (int kt = 0; kt < 16; ++kt) {
    if (kt < 14) STAGE(stg, kt + 2);

    const u16* Kb = &S[cur * 4096];
    const u16* Vb = &S[12288 + cur * 4096];

    f32x4 s[4];
    f32x4 seed = {-m, -m, -m, -m};
    __builtin_amdgcn_s_setprio(1);
    #pragma unroll
    for (int ks = 0; ks < 4; ++ks) {
      int row = ks * 16 + q;
      int4 k0 = *(const int4*)&Kb[row * 64 + ((g ^ qs) * 8)];
      int4 k1 = *(const int4*)&Kb[row * 64 + (((4 + g) ^ qs) * 8)];
      f32x4 sv = seed;
      sv = __builtin_amdgcn_mfma_f32_16x16x32_bf16(__builtin_bit_cast(bf16x8, k0), Qf0, sv, 0, 0, 0);
      sv = __builtin_amdgcn_mfma_f32_16x16x32_bf16(__builtin_bit_cast(bf16x8, k1), Qf1, sv, 0, 0, 0);
      s[ks] = sv;
    }
    __builtin_amdgcn_s_setprio(0);

    float a0 = fmaxf(fmaxf(s[0][0], s[0][1]), s[0][2]);
    float a1 = fmaxf(fmaxf(s[0][3], s[1][0]), s[1][1]);
    float a2 = fmaxf(fmaxf(s[1][2], s[1][3]), s[2][0]);
    float a3 = fmaxf(fmaxf(s[2][1], s[2][2]), s[2][3]);
    float a4 = fmaxf(fmaxf(s[3][0], s[3][1]), s[3][2]);
    float tmx = fmaxf(fmaxf(fmaxf(a0, a1), a2), fmaxf(fmaxf(a3, a4), s[3][3]));

    float p[16];
    if (__builtin_expect(__any(tmx > 8.0f), 0)) {
      float tr = fmaxf(tmx, __shfl_xor(tmx, 16, 64));
      tr = fmaxf(tr, __shfl_xor(tr, 32, 64));
      float dm = fmaxf(tr, 0.f);
      float alpha = exp2f(-dm);
      lsum *= alpha;
      acc[0] *= alpha; acc[1] *= alpha; acc[2] *= alpha; acc[3] *= alpha;
      m += dm;
      #pragma unroll
      for (int ks = 0; ks < 4; ++ks) {
        p[ks * 4 + 0] = exp2f(s[ks][0] - dm);
        p[ks * 4 + 1] = exp2f(s[ks][1] - dm);
        p[ks * 4 + 2] = exp2f(s[ks][2] - dm);
        p[ks * 4 + 3] = exp2f(s[ks][3] - dm);
      }
    } else {
      #pragma unroll
      for (int ks = 0; ks < 4; ++ks) {
        p[ks * 4 + 0] = exp2f(s[ks][0]);
        p[ks * 4 + 1] = exp2f(s[ks][1]);
        p[ks * 4 + 2] = exp2f(s[ks][2]);
        p[ks * 4 + 3] = exp2f(s[ks][3]);
      }
    }
    float q01 = p[0] + p[1],   q23 = p[2] + p[3];
    float q45 = p[4] + p[5],   q67 = p[6] + p[7];
    float q89 = p[8] + p[9],   qab = p[10] + p[11];
    float qcd = p[12] + p[13], qef = p[14] + p[15];
    lsum += ((q01 + q23) + (q45 + q67)) + ((q89 + qab) + (qcd + qef));

    union { u32 w4[4]; bf16x8 v; } pb0, pb1;
    pb0.w4[0] = cvtpk(p[0], p[1]);   pb0.w4[1] = cvtpk(p[2], p[3]);
    pb0.w4[2] = cvtpk(p[4], p[5]);   pb0.w4[3] = cvtpk(p[6], p[7]);
    pb1.w4[0] = cvtpk(p[8], p[9]);   pb1.w4[1] = cvtpk(p[10], p[11]);
    pb1.w4[2] = cvtpk(p[12], p[13]); pb1.w4[3] = cvtpk(p[14], p[15]);

    __builtin_amdgcn_s_setprio(1);
    #pragma unroll
    for (int dt = 0; dt < 4; ++dt) {
      int row = dt * 16 + q;
      int4 v0 = *(const int4*)&Vb[row * 64 + ((g ^ qs) * 8)];
      int4 v1 = *(const int4*)&Vb[row * 64 + (((4 + g) ^ qs) * 8)];
      acc[dt] = __builtin_amdgcn_mfma_f32_16x16x32_bf16(__builtin_bit_cast(bf16x8, v0), pb0.v, acc[dt], 0, 0, 0);
      acc[dt] = __builtin_amdgcn_mfma_f32_16x16x32_bf16(__builtin_bit_cast(bf16x8, v1), pb1.v, acc[dt], 0, 0, 0);
    }
    __builtin_amdgcn_s_setprio(0);

    if (kt < 14) {
      asm volatile("s_waitcnt vmcnt(4)" ::: "memory");
    } else {
      asm volatile("s_waitcnt vmcnt(0)" ::: "memory");
    }
    __builtin_amdgcn_s_barrier();
    __builtin_amdgcn_sched_barrier(0);

    cur = (cur == 2) ? 0 : cur + 1;
    stg = (stg == 2) ? 0 : stg + 1;
  }
  #undef STAGE

  lsum += __shfl_xor(lsum, 16, 64);
  lsum += __shfl_xor(lsum, 32, 64);
  float inv = 1.0f / lsum;

  float* oT = (float*)S + (size_t)w * 1088;   // per-wave 64x17 region
  #pragma unroll
  for (int dt = 0; dt < 4; ++dt) {
    oT[(dt * 16 + g * 4 + 0) * 17 + q] = acc[dt][0] * inv;
    oT[(dt * 16 + g * 4 + 1) * 17 + q] = acc[dt][1] * inv;
    oT[(dt * 16 + g * 4 + 2) * 17 + q] = acc[dt][2] * inv;
    oT[(dt * 16 + g * 4 + 3) * 17 + q] = acc[dt][3] * inv;
  }
  asm volatile("s_waitcnt lgkmcnt(0)" ::: "memory");
  int oq = lane >> 2, dc = (lane & 3) * 16;
  float* orow = out + (size_t)(b * F + q0 + oq) * 1024 + h * 64 + dc;
  #pragma unroll
  for (int c4 = 0; c4 < 4; ++c4) {
    float4 v;
    v.x = oT[(dc + c4 * 4 + 0) * 17 + oq];
    v.y = oT[(dc + c4 * 4 + 1) * 17 + oq];
    v.z = oT[(dc + c4 * 4 + 2) * 17 + oq];
    v.w = oT[(dc + c4 * 4 + 3) * 17 + oq];
    *(float4*)(orow + c4 * 4) = v;
  }
}

// ---------------------------------------------------------------------------
extern "C" void kernel_launch(void* const* d_in, const int* in_sizes, int n_in,
                              void* d_out, int out_size, void* d_ws, size_t ws_size,
                              hipStream_t stream) {
  const float* x     = (const float*)d_in[0];
  const float* gamma = (const float*)d_in[1];
  const float* beta  = (const float*)d_in[2];
  const float* W     = (const float*)d_in[3];
  const float* bias  = (const float*)d_in[4];
  float* out = (float*)d_out;

  char* ws = (char*)d_ws;
  u16* xn  = (u16*)ws;                                   // 16 MB  @ 0
  u16* Wqk = (u16*)(ws + (size_t)16 * 1024 * 1024);      //  4 MB  @ 16M
  u16* Wv  = (u16*)(ws + (size_t)20 * 1024 * 1024);      //  2 MB  @ 20M
  u16* qk  = (u16*)(ws + (size_t)22 * 1024 * 1024);      // 32 MB  @ 22M
  u16* Vt  = (u16*)(ws + (size_t)54 * 1024 * 1024);      // 16 MB  @ 54M

  bn_norm_kernel<<<1024, 256, 0, stream>>>(x, gamma, beta, xn);
  wconv_kernel<<<768, 256, 0, stream>>>(W, Wqk, Wv);
  gemm_qk_kernel<<<dim3(64, 16), 256, 0, stream>>>(xn, Wqk, bias, qk);
  gemm_v_kernel<<<dim3(64, 8), 256, 0, stream>>>(xn, Wv, bias, Vt);
  attn_kernel<<<2048, 256, 0, stream>>>(qk, Vt, out);
}

// Round 12
// 152.515 us; speedup vs baseline: 1.5349x; 1.1322x over previous
//
#include <hip/hip_runtime.h>

typedef unsigned short u16;
typedef unsigned int   u32;

typedef __bf16 bf16x8 __attribute__((ext_vector_type(8)));
typedef float  f32x4  __attribute__((ext_vector_type(4)));

typedef const __attribute__((address_space(1))) void* gas_ptr;
typedef __attribute__((address_space(3))) void* las_ptr;

__device__ __forceinline__ u16 f2bf(float f) {
  u32 u = __builtin_bit_cast(u32, f);
  u += 0x7fffu + ((u >> 16) & 1u);
  return (u16)(u >> 16);
}
__device__ __forceinline__ float bf2f(u16 u) {
  return __builtin_bit_cast(float, ((u32)u) << 16);
}
// packed f32->bf16x2 hardware convert (RTNE), 1 VALU op per pair
__device__ __forceinline__ u32 cvtpk(float a, float b) {
  u32 r;
  asm("v_cvt_pk_bf16_f32 %0, %1, %2" : "=v"(r) : "v"(a), "v"(b));
  return r;
}
// raw v_exp_f32 (2^x, ~1ulp) — bypasses any guarded libm expansion
__device__ __forceinline__ float fexp2(float x) {
  return __builtin_amdgcn_exp2f(x);
}

// ---------------------------------------------------------------------------
// Kernel 1: BatchNorm over F-channels (stats over B,E) + bf16 cast.
// ---------------------------------------------------------------------------
__global__ __launch_bounds__(256) void bn_norm_kernel(
    const float* __restrict__ x, const float* __restrict__ gamma,
    const float* __restrict__ beta, u16* __restrict__ xn) {
  const int F = 1024, E = 1024;
  int f = blockIdx.x;
  __shared__ float sh[8192];
  __shared__ float ps[4], pq[4], sc[2];

  const float* xf = x + (size_t)f * E;
  float ls = 0.f, lq = 0.f;
  for (int i = threadIdx.x; i < 8192; i += 256) {
    int b = i >> 10, e = i & 1023;
    float v = xf[(size_t)b * F * E + e];
    sh[i] = v;
    ls += v;
    lq += v * v;
  }
  #pragma unroll
  for (int o = 32; o > 0; o >>= 1) {
    ls += __shfl_down(ls, o, 64);
    lq += __shfl_down(lq, o, 64);
  }
  int w = threadIdx.x >> 6;
  if ((threadIdx.x & 63) == 0) { ps[w] = ls; pq[w] = lq; }
  __syncthreads();
  if (threadIdx.x == 0) {
    float s = ps[0] + ps[1] + ps[2] + ps[3];
    float q = pq[0] + pq[1] + pq[2] + pq[3];
    float mean = s * (1.f / 8192.f);
    float var = q * (1.f / 8192.f) - mean * mean;
    float scale = gamma[f] * rsqrtf(var + 1e-5f);
    sc[0] = scale;
    sc[1] = beta[f] - mean * scale;
  }
  __syncthreads();
  float scale = sc[0], shift = sc[1];
  for (int i = threadIdx.x; i < 8192; i += 256) {
    int b = i >> 10, e = i & 1023;
    xn[((size_t)(b * F + f)) * E + e] = f2bf(sh[i] * scale + shift);
  }
}

// ---------------------------------------------------------------------------
// Kernel 2: W_qkv f32 -> bf16
// ---------------------------------------------------------------------------
__global__ __launch_bounds__(256) void wconv_kernel(
    const float* __restrict__ W, u16* __restrict__ Wb) {
  const int total = 3072 * 1024 / 4;
  for (int i = blockIdx.x * 256 + threadIdx.x; i < total; i += gridDim.x * 256) {
    float4 v = ((const float4*)W)[i];
    ushort4 o;
    o.x = f2bf(v.x); o.y = f2bf(v.y); o.z = f2bf(v.z); o.w = f2bf(v.w);
    ((ushort4*)Wb)[i] = o;
  }
}

// ---------------------------------------------------------------------------
// Kernel 3: GEMM  C[m][n] = sum_k A[m][k]*Bw[n][k] + bias[n]  (m97 structure)
// ---------------------------------------------------------------------------
__global__ __launch_bounds__(256) void gemm_qkv_kernel(
    const u16* __restrict__ A, const u16* __restrict__ Bw,
    const float* __restrict__ bias, u16* __restrict__ C) {
  const int K = 1024, N = 3072;
  __shared__ u16 As[128 * 32];
  __shared__ u16 Bs[128 * 32];

  int m0 = blockIdx.x * 128, n0 = blockIdx.y * 128;
  int t = threadIdx.x, lane = t & 63, w = t >> 6;
  int wr = w >> 1, wc = w & 1;
  int r = lane & 15, g = lane >> 4;

  int srow = t >> 2, scol = (t & 3) * 8;
  const u16* gA  = A  + (size_t)(m0 + srow) * K + scol;
  const u16* gA2 = gA + (size_t)64 * K;
  const u16* gB  = Bw + (size_t)(n0 + srow) * K + scol;
  const u16* gB2 = gB + (size_t)64 * K;
  u16* lA  = As + t * 8;
  u16* lA2 = As + 2048 + t * 8;
  u16* lB  = Bs + t * 8;
  u16* lB2 = Bs + 2048 + t * 8;

  f32x4 acc[4][4] = {};

  const u16* pA = As + (size_t)(wr * 64 + r) * 32 + g * 8;
  const u16* pB = Bs + (size_t)(wc * 64 + r) * 32 + g * 8;

  for (int k0 = 0; k0 < K; k0 += 32) {
    __builtin_amdgcn_global_load_lds((gas_ptr)gA,  (las_ptr)lA,  16, 0, 0);
    __builtin_amdgcn_global_load_lds((gas_ptr)gA2, (las_ptr)lA2, 16, 0, 0);
    __builtin_amdgcn_global_load_lds((gas_ptr)gB,  (las_ptr)lB,  16, 0, 0);
    __builtin_amdgcn_global_load_lds((gas_ptr)gB2, (las_ptr)lB2, 16, 0, 0);
    gA += 32; gA2 += 32; gB += 32; gB2 += 32;
    __syncthreads();

    bf16x8 af[4], bfr[4];
    #pragma unroll
    for (int mi = 0; mi < 4; ++mi)
      af[mi] = __builtin_bit_cast(bf16x8, *(const int4*)(pA + mi * 512));
    #pragma unroll
    for (int ni = 0; ni < 4; ++ni)
      bfr[ni] = __builtin_bit_cast(bf16x8, *(const int4*)(pB + ni * 512));
    #pragma unroll
    for (int mi = 0; mi < 4; ++mi)
      #pragma unroll
      for (int ni = 0; ni < 4; ++ni)
        acc[mi][ni] = __builtin_amdgcn_mfma_f32_16x16x32_bf16(af[mi], bfr[ni], acc[mi][ni], 0, 0, 0);
    __syncthreads();
  }

  #pragma unroll
  for (int ni = 0; ni < 4; ++ni) {
    int col = n0 + wc * 64 + ni * 16 + r;
    float bv = bias[col];
    #pragma unroll
    for (int mi = 0; mi < 4; ++mi) {
      int row = m0 + wr * 64 + mi * 16 + g * 4;
      #pragma unroll
      for (int j = 0; j < 4; ++j)
        C[(size_t)(row + j) * N + col] = f2bf(acc[mi][ni][j] + bv);
    }
  }
}

// ---------------------------------------------------------------------------
// Kernel 3b: V transpose WITH baked key permutation (verified R3).
//   Vt[bh][d][kb+m] = V[kb + a(m)][d],  a(m) = bits (m2 m4 m3 m1 m0)
// so the in-register QK softmax output IS the PV B-fragment.
// ---------------------------------------------------------------------------
__global__ __launch_bounds__(256) void vt_kernel(
    const u16* __restrict__ qkv, u16* __restrict__ Vt) {
  __shared__ u16 T[64][72];
  int bh = blockIdx.y, b = bh >> 4, h = bh & 15;
  int f0 = blockIdx.x * 64;
  int t = threadIdx.x;
  int fl = t >> 2, c16 = (t & 3) * 16;
  const u16* src = qkv + (size_t)(b * 1024 + f0 + fl) * 3072 + h * 192 + 128 + c16;
  *(int4*)&T[fl][c16]     = *(const int4*)src;
  *(int4*)&T[fl][c16 + 8] = *(const int4*)(src + 8);
  __syncthreads();
  int dl = t >> 2, fc = (t & 3) * 16;
  u16 buf[16];
  #pragma unroll
  for (int j = 0; j < 16; ++j) {
    int c = fc + j;
    int m = c & 31;
    int a = ((m & 4) << 2) | ((m & 16) >> 1) | ((m & 8) >> 1) | (m & 3);
    buf[j] = T[(c & 32) | a][dl];
  }
  u16* dst = Vt + (size_t)bh * 65536 + (size_t)dl * 1024 + f0 + fc;
  *(int4*)dst       = *(int4*)&buf[0];
  *(int4*)(dst + 8) = *(int4*)&buf[8];
}

// ---------------------------------------------------------------------------
// Kernel 4: flash attention v9 — R7 structure + raw v_exp_f32 + full unroll.
//  - all exp2 via __builtin_amdgcn_exp2f (single VALU-trans instr).
//  - 16-tile loop fully unrolled: buffer indices & stage offsets are
//    compile-time constants (no per-tile address VALU).
//  - triple-buffered K/V, counted-vmcnt (vmcnt(4)) pipeline, prefetch depth 2.
// ---------------------------------------------------------------------------
__global__ __launch_bounds__(256) void attn_kernel(
    const u16* __restrict__ qkv, const u16* __restrict__ Vt,
    float* __restrict__ out) {
  const int F = 1024, NQ = 3072;
  int bid = blockIdx.x;           // 2048 blocks
  int xcd = bid & 7;
  int li  = bid >> 3;             // 0..255
  int bh  = ((li >> 4) << 3) | xcd;
  int ql  = li & 15;
  int w   = threadIdx.x >> 6;
  int lane = threadIdx.x & 63;
  int q = lane & 15, g = lane >> 4;
  int qs = q & 7;
  int q0 = ql * 64 + w * 16;
  int b = bh >> 4, h = bh & 15;

  const u16* base = qkv + (size_t)b * F * NQ + h * 192;
  const u16* VtBH = Vt + (size_t)bh * 65536;

  // 3 K bufs @ 0/4096/8192, 3 V bufs @ 12288/16384/20480 (u16 units; 48 KB)
  __shared__ u16 S[24576];

  int i8 = lane >> 3;     // staging row within wave's slice
  int ic = lane & 7;      // staging chunk (16B units)

  const float qscale = 0.125f * 1.4426950408889634f;
  bf16x8 Qf0, Qf1;
  {
    const u16* qp = base + (size_t)(q0 + q) * NQ + g * 8;
    union { int4 v; u16 u[8]; } uu0, uu1;
    uu0.v = *(const int4*)(qp);
    uu1.v = *(const int4*)(qp + 32);
    union { u32 w4[4]; bf16x8 v; } p0, p1;
    #pragma unroll
    for (int j = 0; j < 4; ++j) {
      p0.w4[j] = cvtpk(bf2f(uu0.u[2 * j]) * qscale, bf2f(uu0.u[2 * j + 1]) * qscale);
      p1.w4[j] = cvtpk(bf2f(uu1.u[2 * j]) * qscale, bf2f(uu1.u[2 * j + 1]) * qscale);
    }
    Qf0 = p0.v; Qf1 = p1.v;
  }

  f32x4 acc[4] = {};
  float m = 0.0f, lsum = 0.f;   // m=0 init (C-seeding needs finite m)

  #define STAGE(buf, kt)                                                       \
    do {                                                                       \
      int kb_ = (kt) * 64;                                                     \
      _Pragma("unroll")                                                        \
      for (int rr = 0; rr < 2; ++rr) {                                         \
        int r_ = rr * 32 + w * 8 + i8;                                         \
        int sc_ = (ic ^ (r_ & 7)) * 8;                                         \
        const u16* ks_ = base + (size_t)(kb_ + r_) * NQ + 64 + sc_;            \
        const u16* vs_ = VtBH + (size_t)r_ * 1024 + kb_ + sc_;                 \
        __builtin_amdgcn_global_load_lds((gas_ptr)ks_,                         \
            (las_ptr)&S[(buf) * 4096 + (rr * 32 + w * 8) * 64], 16, 0, 0);     \
        __builtin_amdgcn_global_load_lds((gas_ptr)vs_,                         \
            (las_ptr)&S[12288 + (buf) * 4096 + (rr * 32 + w * 8) * 64], 16, 0, 0);\
      }                                                                        \
    } while (0)

  __builtin_amdgcn_sched_barrier(0);
  STAGE(0, 0);
  STAGE(1, 1);
  asm volatile("s_waitcnt vmcnt(4)" ::: "memory");
  __builtin_amdgcn_s_barrier();
  __builtin_amdgcn_sched_barrier(0);

  #pragma unroll
  for (int kt = 0; kt < 16; ++kt) {
    const int cur = kt % 3;                 // compile-time after unroll
    const int stg = (kt + 2) % 3;
    if (kt < 14) STAGE(stg, kt + 2);

    const u16* Kb = &S[cur * 4096];
    const u16* Vb = &S[12288 + cur * 4096];

    f32x4 s[4];
    f32x4 seed = {-m, -m, -m, -m};
    __builtin_amdgcn_s_setprio(1);
    #pragma unroll
    for (int ks = 0; ks < 4; ++ks) {
      int row = ks * 16 + q;
      int4 k0 = *(const int4*)&Kb[row * 64 + ((g ^ qs) * 8)];
      int4 k1 = *(const int4*)&Kb[row * 64 + (((4 + g) ^ qs) * 8)];
      f32x4 sv = seed;
      sv = __builtin_amdgcn_mfma_f32_16x16x32_bf16(__builtin_bit_cast(bf16x8, k0), Qf0, sv, 0, 0, 0);
      sv = __builtin_amdgcn_mfma_f32_16x16x32_bf16(__builtin_bit_cast(bf16x8, k1), Qf1, sv, 0, 0, 0);
      s[ks] = sv;
    }
    __builtin_amdgcn_s_setprio(0);

    float a0 = fmaxf(fmaxf(s[0][0], s[0][1]), s[0][2]);
    float a1 = fmaxf(fmaxf(s[0][3], s[1][0]), s[1][1]);
    float a2 = fmaxf(fmaxf(s[1][2], s[1][3]), s[2][0]);
    float a3 = fmaxf(fmaxf(s[2][1], s[2][2]), s[2][3]);
    float a4 = fmaxf(fmaxf(s[3][0], s[3][1]), s[3][2]);
    float tmx = fmaxf(fmaxf(fmaxf(a0, a1), a2), fmaxf(fmaxf(a3, a4), s[3][3]));

    float p[16];
    if (__builtin_expect(__any(tmx > 8.0f), 0)) {
      float tr = fmaxf(tmx, __shfl_xor(tmx, 16, 64));
      tr = fmaxf(tr, __shfl_xor(tr, 32, 64));
      float dm = fmaxf(tr, 0.f);
      float alpha = fexp2(-dm);
      lsum *= alpha;
      acc[0] *= alpha; acc[1] *= alpha; acc[2] *= alpha; acc[3] *= alpha;
      m += dm;
      #pragma unroll
      for (int ks = 0; ks < 4; ++ks) {
        p[ks * 4 + 0] = fexp2(s[ks][0] - dm);
        p[ks * 4 + 1] = fexp2(s[ks][1] - dm);
        p[ks * 4 + 2] = fexp2(s[ks][2] - dm);
        p[ks * 4 + 3] = fexp2(s[ks][3] - dm);
      }
    } else {
      #pragma unroll
      for (int ks = 0; ks < 4; ++ks) {
        p[ks * 4 + 0] = fexp2(s[ks][0]);
        p[ks * 4 + 1] = fexp2(s[ks][1]);
        p[ks * 4 + 2] = fexp2(s[ks][2]);
        p[ks * 4 + 3] = fexp2(s[ks][3]);
      }
    }
    float q01 = p[0] + p[1],   q23 = p[2] + p[3];
    float q45 = p[4] + p[5],   q67 = p[6] + p[7];
    float q89 = p[8] + p[9],   qab = p[10] + p[11];
    float qcd = p[12] + p[13], qef = p[14] + p[15];
    lsum += ((q01 + q23) + (q45 + q67)) + ((q89 + qab) + (qcd + qef));

    union { u32 w4[4]; bf16x8 v; } pb0, pb1;
    pb0.w4[0] = cvtpk(p[0], p[1]);   pb0.w4[1] = cvtpk(p[2], p[3]);
    pb0.w4[2] = cvtpk(p[4], p[5]);   pb0.w4[3] = cvtpk(p[6], p[7]);
    pb1.w4[0] = cvtpk(p[8], p[9]);   pb1.w4[1] = cvtpk(p[10], p[11]);
    pb1.w4[2] = cvtpk(p[12], p[13]); pb1.w4[3] = cvtpk(p[14], p[15]);

    __builtin_amdgcn_s_setprio(1);
    #pragma unroll
    for (int dt = 0; dt < 4; ++dt) {
      int row = dt * 16 + q;
      int4 v0 = *(const int4*)&Vb[row * 64 + ((g ^ qs) * 8)];
      int4 v1 = *(const int4*)&Vb[row * 64 + (((4 + g) ^ qs) * 8)];
      acc[dt] = __builtin_amdgcn_mfma_f32_16x16x32_bf16(__builtin_bit_cast(bf16x8, v0), pb0.v, acc[dt], 0, 0, 0);
      acc[dt] = __builtin_amdgcn_mfma_f32_16x16x32_bf16(__builtin_bit_cast(bf16x8, v1), pb1.v, acc[dt], 0, 0, 0);
    }
    __builtin_amdgcn_s_setprio(0);

    if (kt < 14) {
      asm volatile("s_waitcnt vmcnt(4)" ::: "memory");
    } else {
      asm volatile("s_waitcnt vmcnt(0)" ::: "memory");
    }
    __builtin_amdgcn_s_barrier();
    __builtin_amdgcn_sched_barrier(0);
  }
  #undef STAGE

  lsum += __shfl_xor(lsum, 16, 64);
  lsum += __shfl_xor(lsum, 32, 64);
  float inv = 1.0f / lsum;

  float* oT = (float*)S + (size_t)w * 1088;   // per-wave 64x17 region
  #pragma unroll
  for (int dt = 0; dt < 4; ++dt) {
    oT[(dt * 16 + g * 4 + 0) * 17 + q] = acc[dt][0] * inv;
    oT[(dt * 16 + g * 4 + 1) * 17 + q] = acc[dt][1] * inv;
    oT[(dt * 16 + g * 4 + 2) * 17 + q] = acc[dt][2] * inv;
    oT[(dt * 16 + g * 4 + 3) * 17 + q] = acc[dt][3] * inv;
  }
  asm volatile("s_waitcnt lgkmcnt(0)" ::: "memory");
  int oq = lane >> 2, dc = (lane & 3) * 16;
  float* orow = out + (size_t)(b * F + q0 + oq) * 1024 + h * 64 + dc;
  #pragma unroll
  for (int c4 = 0; c4 < 4; ++c4) {
    float4 v;
    v.x = oT[(dc + c4 * 4 + 0) * 17 + oq];
    v.y = oT[(dc + c4 * 4 + 1) * 17 + oq];
    v.z = oT[(dc + c4 * 4 + 2) * 17 + oq];
    v.w = oT[(dc + c4 * 4 + 3) * 17 + oq];
    *(float4*)(orow + c4 * 4) = v;
  }
}

// ---------------------------------------------------------------------------
extern "C" void kernel_launch(void* const* d_in, const int* in_sizes, int n_in,
                              void* d_out, int out_size, void* d_ws, size_t ws_size,
                              hipStream_t stream) {
  const float* x     = (const float*)d_in[0];
  const float* gamma = (const float*)d_in[1];
  const float* beta  = (const float*)d_in[2];
  const float* W     = (const float*)d_in[3];
  const float* bias  = (const float*)d_in[4];
  float* out = (float*)d_out;

  char* ws = (char*)d_ws;
  u16* xn  = (u16*)ws;                                   // 16 MB
  u16* Wb  = (u16*)(ws + (size_t)16 * 1024 * 1024);      //  6 MB
  u16* qkv = (u16*)(ws + (size_t)22 * 1024 * 1024);      // 48 MB
  u16* Vt  = (u16*)(ws + (size_t)70 * 1024 * 1024);      // 16 MB

  bn_norm_kernel<<<1024, 256, 0, stream>>>(x, gamma, beta, xn);
  wconv_kernel<<<768, 256, 0, stream>>>(W, Wb);
  gemm_qkv_kernel<<<dim3(64, 24), 256, 0, stream>>>(xn, Wb, bias, qkv);
  vt_kernel<<<dim3(16, 128), 256, 0, stream>>>(qkv, Vt);
  attn_kernel<<<2048, 256, 0, stream>>>(qkv, Vt, out);
}